// Round 6
// baseline (197.866 us; speedup 1.0000x reference)
//
#include <hip/hip_runtime.h>

// Problem constants
#define NSEQ 64
#define LL   256
#define DD   256
#define HH   8
#define HDIM 32

typedef short short8  __attribute__((ext_vector_type(8)));
typedef short short4v __attribute__((ext_vector_type(4)));
typedef float float4v __attribute__((ext_vector_type(4)));

#define MFMA16(a,b,c) __builtin_amdgcn_mfma_f32_16x16x32_bf16((a),(b),(c),0,0,0)

__device__ __forceinline__ float4v zero4() {
  float4v z;
  z[0] = 0.f; z[1] = 0.f; z[2] = 0.f; z[3] = 0.f;
  return z;
}

__device__ __forceinline__ short f2b(float f) {
  unsigned u = __float_as_uint(f);
  u = (u + 0x7fffu + ((u >> 16) & 1u)) >> 16;   // RNE
  return (short)u;
}

__device__ __forceinline__ float b2f(short s) {
  return __uint_as_float(((unsigned)(unsigned short)s) << 16);
}

// async global->LDS, 16B per lane. LDS dest must be wave-uniform-base + lane*16.
__device__ __forceinline__ void ld_lds16(const void* g, void* l) {
  __builtin_amdgcn_global_load_lds(
      (const __attribute__((address_space(1))) unsigned int*)g,
      (__attribute__((address_space(3))) unsigned int*)l, 16, 0, 0);
}
#define WAIT_VM0() __builtin_amdgcn_s_waitcnt(0x0F70)   // vmcnt(0) only

// ---- workspace layout (bytes); total ~34.5 MB (MSA16 and O share) ----
#define WT_OFF    0                            // 4 x 256x256 bf16 (Wq^T,Wk^T,Wv^T,Wo^T) [ch][k]
#define PB_OFF    (4*65536*2)                  // pb bf16 [h][i][j] (1MB) + fragments (1MB)
#define PBF_OFF   (PB_OFF + 8*65536*2)         // pb bf16 fragments [h][it][jt][lane][4]
#define Q_OFF     (PB_OFF + 8*65536*4)         // per-head q_h[n][h][i][hd] bf16
#define K_OFF     (Q_OFF  + 16384*256*2)       // per-head k_h[n][h][j][hd] bf16
#define VT_OFF    (K_OFF  + 16384*256*2)       // [n][h][hd][j] bf16
#define MSA16_OFF (VT_OFF + 16384*256*2)       // 16384x256 bf16 (dead after k2)
#define O_OFF     MSA16_OFF                    // k3 output overlays MSA16

// ============================================================================
// INSTRUMENTATION ROUND: every kernel's grid is DOUBLED (bx >= N -> bx - N).
// Duplicate blocks redo identical work (idempotent writes) so each dispatch
// lasts ~2x its true time -> the big kernels rise above the 42us fillBuffer
// rows in the top-5 counter table and get fully profiled. Revert next round.
// ============================================================================

// ============================================================================
// K1: pb GEMM (256) + weight transpose via LDS (64) + msa->bf16 (512)
//     = 832 logical blocks, launched x2.
// ============================================================================
__global__ __launch_bounds__(256) void k1_prep(
    const float* __restrict__ msa,  const float* __restrict__ pair,
    const float* __restrict__ Wq,   const float* __restrict__ Wk,
    const float* __restrict__ Wv,   const float* __restrict__ Wpb,
    const float* __restrict__ bpb,  const float* __restrict__ Wo,
    char* __restrict__ ws)
{
  __shared__ __align__(16) short shm[4 * 64 * 128];   // 64KB: pair staging / transpose tile
  __shared__ short ldsWt[16 * 136];   // Wpb^T bf16, rows 8..15 zero, ld=136 (pad)
  int bx = blockIdx.x, tid = threadIdx.x;
  if (bx >= 832) bx -= 832;           // duplicate half (instrumentation)
  if (bx < 256) {
    short* pb16 = (short*)(ws + PB_OFF);
    for (int i = tid; i < 16 * 136; i += 256) ldsWt[i] = 0;
    __syncthreads();
    {
      float4 wv4 = *(const float4*)&Wpb[tid * 4];
      int kk = (tid * 4) >> 3, n0 = (tid * 4) & 7;
      ldsWt[(n0 + 0) * 136 + kk] = f2b(wv4.x);
      ldsWt[(n0 + 1) * 136 + kk] = f2b(wv4.y);
      ldsWt[(n0 + 2) * 136 + kk] = f2b(wv4.z);
      ldsWt[(n0 + 3) * 136 + kk] = f2b(wv4.w);
    }
    __syncthreads();
    int w = tid >> 6, l = tid & 63, q = l >> 4, c = l & 15;
    int base = bx * 256 + w * 64;          // block bx covers pair row i=bx, all j
    // stage pair[base .. base+64)[0..128) -> bf16 LDS, coalesced + swizzled
    short* lsWw = shm + w * 8192;
#pragma unroll
    for (int it = 0; it < 16; it++) {
      int jl = it * 4 + (l >> 4);
      int kc = l & 15;
      const float* src = &pair[(base + jl) * 128 + kc * 8];
      float4 a = *(const float4*)src;
      float4 b = *(const float4*)(src + 4);
      short8 v8;
      v8[0] = f2b(a.x); v8[1] = f2b(a.y); v8[2] = f2b(a.z); v8[3] = f2b(a.w);
      v8[4] = f2b(b.x); v8[5] = f2b(b.y); v8[6] = f2b(b.z); v8[7] = f2b(b.w);
      *(short8*)&lsWw[jl * 128 + ((kc ^ (jl & 7)) * 8)] = v8;
    }
    float bias = bpb[c & 7];
    short8 bf[4];
#pragma unroll
    for (int ks = 0; ks < 4; ks++)
      bf[ks] = *(const short8*)&ldsWt[c * 136 + ks * 32 + q * 8];
    float4v acc[4];
#pragma unroll
    for (int mt = 0; mt < 4; mt++) acc[mt] = zero4();
#pragma unroll
    for (int ks = 0; ks < 4; ks++) {
#pragma unroll
      for (int mt = 0; mt < 4; mt++) {
        int row = mt * 16 + c;
        short8 af = *(const short8*)&lsWw[row * 128 + (((ks * 4 + q) ^ (c & 7)) * 8)];
        acc[mt] = MFMA16(af, bf[ks], acc[mt]);
      }
    }
    if (c < 8) {
#pragma unroll
      for (int mt = 0; mt < 4; mt++) {
        short4v o;
#pragma unroll
        for (int r = 0; r < 4; r++) o[r] = f2b(acc[mt][r] + bias);
        *(short4v*)&pb16[c * 65536 + base + mt * 16 + q * 4] = o;
      }
    }
  } else if (bx < 320) {
    // weight transpose via LDS: 64 blocks, each a 64(k) x 64(n) tile
    int b2 = bx - 256;                  // 0..63
    int mat = b2 >> 4, sub = b2 & 15;
    int k0 = (sub >> 2) * 64, n0 = (sub & 3) * 64;
    const float* W = (mat == 0) ? Wq : (mat == 1) ? Wk : (mat == 2) ? Wv : Wo;
    short* wt = (short*)(ws + WT_OFF) + mat * 65536;
    short* ldsT = shm;                  // 64 x 72
#pragma unroll
    for (int p = 0; p < 4; p++) {
      int kl = p * 16 + (tid >> 4);
      int nl = (tid & 15) * 4;
      float4 v = *(const float4*)&W[(k0 + kl) * 256 + n0 + nl];
      ldsT[(nl + 0) * 72 + kl] = f2b(v.x);
      ldsT[(nl + 1) * 72 + kl] = f2b(v.y);
      ldsT[(nl + 2) * 72 + kl] = f2b(v.z);
      ldsT[(nl + 3) * 72 + kl] = f2b(v.w);
    }
    __syncthreads();
#pragma unroll
    for (int p = 0; p < 2; p++) {
      int id = p * 256 + tid;
      int nl = id >> 3, c8 = id & 7;
      *(short8*)&wt[(n0 + nl) * 256 + k0 + c8 * 8] =
          *(const short8*)&ldsT[nl * 72 + c8 * 8];
    }
  } else {
    // msa -> bf16 row-major
    int b3 = bx - 320;                  // 0..511, 32 rows each
    const float* src = msa + b3 * 8192;
    short* dst = (short*)(ws + MSA16_OFF) + b3 * 8192;
#pragma unroll
    for (int i = 0; i < 8; i++) {
      int idx = i * 1024 + tid * 4;
      float4 v = *(const float4*)&src[idx];
      short4v s;
      s[0] = f2b(v.x); s[1] = f2b(v.y); s[2] = f2b(v.z); s[3] = f2b(v.w);
      *(short4v*)&dst[idx] = s;
    }
  }
}

// ============================================================================
// K2: QKV GEMM (768) + pb repack (128) = 896 logical blocks, launched x2.
// ============================================================================
__global__ __launch_bounds__(256) void k2_qkv(
    const float* __restrict__ bq, const float* __restrict__ bk,
    const float* __restrict__ bv, char* __restrict__ ws)
{
  __shared__ __align__(16) short ls[2 * 128 * 128];   // lsA | lsB, reused as lsC
  short* lsA = ls;
  short* lsB = ls + 16384;
  int bx = blockIdx.x, tid = threadIdx.x;
  if (bx >= 896) bx -= 896;           // duplicate half (instrumentation)
  if (bx >= 768) {
    // pb repack: pb16[h][i][j] -> fragments pbf[h][it][jt][lane][reg] (bf16)
    int b = bx - 768;                   // 0..127
    int it16 = b & 15;
    const short* src = (const short*)(ws + PB_OFF) + (b >> 4) * 65536 + it16 * 4096;
    short* pbf = (short*)(ws + PBF_OFF);
    short* lt = lsA;                    // 16 x 264
#pragma unroll
    for (int i2 = 0; i2 < 2; i2++) {
      int idx = i2 * 2048 + tid * 8;
      *(short8*)&lt[(idx >> 8) * 264 + (idx & 255)] = *(const short8*)&src[idx];
    }
    __syncthreads();
#pragma unroll
    for (int i2 = 0; i2 < 4; i2++) {
      int fid = i2 * 256 + tid;
      int jt = fid >> 6, lane = fid & 63;
      int qp = lane >> 4, cp = lane & 15;
      short4v v;
#pragma unroll
      for (int r = 0; r < 4; r++)
        v[r] = lt[(qp * 4 + r) * 264 + jt * 16 + cp];
      *(short4v*)&pbf[((b * 16 + jt) * 64 + lane) * 4] = v;
    }
    return;
  }
  int rt = bx & 127, ct = bx >> 7;       // row-tile, col-tile
  int m = ct >> 1, cb = (ct & 1) * 128;  // matrix, ch base within matrix
  int R0 = rt * 128;
  const short* msa16 = (const short*)(ws + MSA16_OFF);
  const short* wt = (const short*)(ws + WT_OFF) + m * 65536;
  int w = tid >> 6, l = tid & 63, q = l >> 4, c = l & 15;
  int WR = (w & 1) * 64, WC = (w >> 1) * 64;
  float4v acc[4][4];
#pragma unroll
  for (int mt = 0; mt < 4; mt++)
#pragma unroll
    for (int nt = 0; nt < 4; nt++) acc[mt][nt] = zero4();

#pragma unroll 1
  for (int kk = 0; kk < 2; kk++) {
    if (kk) __syncthreads();
#pragma unroll
    for (int i = 0; i < 8; i++) {
      int ci = i * 256 + tid;
      int r = ci >> 4, pos = ci & 15;
      int kc = pos ^ (r & 7);
      ld_lds16(&msa16[(R0 + r) * 256 + kk * 128 + kc * 8], &lsA[ci * 8]);
    }
#pragma unroll
    for (int i = 0; i < 8; i++) {
      int ci = i * 256 + tid;
      int r = ci >> 4, pos = ci & 15;
      int kc = pos ^ (r & 7);
      ld_lds16(&wt[(cb + r) * 256 + kk * 128 + kc * 8], &lsB[ci * 8]);
    }
    WAIT_VM0();
    __syncthreads();
#pragma unroll
    for (int ks = 0; ks < 4; ks++) {
      short8 af[4], bf[4];
#pragma unroll
      for (int mt = 0; mt < 4; mt++) {
        int r = WR + mt * 16 + c;
        int phys = (ks * 4 + q) ^ (r & 7);
        af[mt] = *(const short8*)&lsA[r * 128 + phys * 8];
      }
#pragma unroll
      for (int nt = 0; nt < 4; nt++) {
        int r = WC + nt * 16 + c;
        int phys = (ks * 4 + q) ^ (r & 7);
        bf[nt] = *(const short8*)&lsB[r * 128 + phys * 8];
      }
#pragma unroll
      for (int mt = 0; mt < 4; mt++)
#pragma unroll
        for (int nt = 0; nt < 4; nt++)
          acc[mt][nt] = MFMA16(af[mt], bf[nt], acc[mt][nt]);
    }
  }

  const float* bp = (m == 0) ? bq : (m == 1) ? bk : bv;
  int n = R0 >> 8;
  __syncthreads();                      // all waves done reading lsA/lsB
  short* lsC = ls;                      // 128 x 136 bf16
  if (m < 2) {
    // lsC[i][ch] then coalesced per-head-packed store dst[n][h][i][hd]
#pragma unroll
    for (int nt = 0; nt < 4; nt++) {
      float bb = bp[cb + WC + nt * 16 + c];
#pragma unroll
      for (int mt = 0; mt < 4; mt++)
#pragma unroll
        for (int r = 0; r < 4; r++)
          lsC[(WR + mt * 16 + q * 4 + r) * 136 + WC + nt * 16 + c] =
              f2b(acc[mt][nt][r] + bb);
    }
    __syncthreads();
    short* dst = (short*)(ws + (m == 0 ? Q_OFF : K_OFF)) + n * 65536;
    int ibase = R0 & 255;
#pragma unroll
    for (int p = 0; p < 8; p++) {
      int id = p * 256 + tid;
      int il = id >> 4, ch8 = id & 15;
      int chg = cb + ch8 * 8;
      int hh = chg >> 5, hd0 = chg & 31;
      *(short8*)&dst[(hh * 256 + ibase + il) * 32 + hd0] =
          *(const short8*)&lsC[il * 136 + ch8 * 8];
    }
  } else {
    // lsC[ch][j] then coalesced store vt[n*256+ch][j]
#pragma unroll
    for (int nt = 0; nt < 4; nt++) {
      float bb = bp[cb + WC + nt * 16 + c];
#pragma unroll
      for (int mt = 0; mt < 4; mt++)
#pragma unroll
        for (int r = 0; r < 4; r++)
          lsC[(WC + nt * 16 + c) * 136 + WR + mt * 16 + q * 4 + r] =
              f2b(acc[mt][nt][r] + bb);
    }
    __syncthreads();
    short* vt = (short*)(ws + VT_OFF) + n * 65536;
    int jbase = R0 & 255;
#pragma unroll
    for (int p = 0; p < 8; p++) {
      int id = p * 256 + tid;
      int chl = id >> 4, j8 = id & 15;
      int chg = cb + chl;
      *(short8*)&vt[chg * 256 + jbase + j8 * 8] =
          *(const short8*)&lsC[chl * 136 + j8 * 8];
    }
  }
}

// ============================================================================
// K3: attention. 2048 logical blocks, launched x2.
// ============================================================================
__global__ __launch_bounds__(256) void k3_attn(char* __restrict__ ws)
{
  __shared__ __align__(16) short lds[25088];   // 50176 B
  short* lsK = lds;
  short* lsP = lds;
  short* lsV = lds + 16896;
  int bx = blockIdx.x, tid = threadIdx.x;
  if (bx >= 2048) bx -= 2048;         // duplicate half (instrumentation)
  int qq = bx >> 9, grp = bx & 511;
  int n = grp >> 3, h = grp & 7;
  int w = tid >> 6, l = tid & 63, q = l >> 4, c = l & 15;
  const short* qh = (const short*)(ws + Q_OFF) + (n * HH + h) * 256 * HDIM;
  const short* kh = (const short*)(ws + K_OFF) + (n * HH + h) * 256 * HDIM;
  const short* vt = (const short*)(ws + VT_OFF) + (n * HH + h) * HDIM * 256;
  const short* pbf = (const short*)(ws + PBF_OFF) + (h * 16 + qq * 4 + w) * 16 * 256;
  short* os = (short*)(ws + O_OFF);
  const float scale = 0.17677669529663687f;   // 1/sqrt(32)
  int i0 = qq * 64 + w * 16;             // this wave's 16 query rows

  short8 aq = *(const short8*)&qh[(i0 + c) * HDIM + q * 8];

#pragma unroll
  for (int i = 0; i < 4; i++) {
    int ci = i * 256 + tid;
    ld_lds16(&kh[ci * 8], &lsK[ci * 8]);
  }
#pragma unroll
  for (int i = 0; i < 4; i++) {
    int ci = i * 256 + tid;
    int row = ci >> 5, j = ci & 31;
    int sj = j ^ (row & 7);
    ld_lds16(&vt[row * 256 + sj * 8], &lsV[ci * 8]);
  }
  WAIT_VM0();
  __syncthreads();

  float4v s[16];
#pragma unroll
  for (int jt = 0; jt < 16; jt++) {
    short8 bk8 = *(const short8*)&lsK[(jt * 16 + c) * 32 + q * 8];
    s[jt] = MFMA16(aq, bk8, zero4());
  }
#pragma unroll
  for (int jt = 0; jt < 16; jt++) {
    short4v pv = *(const short4v*)&pbf[(jt * 64 + l) * 4];
#pragma unroll
    for (int r = 0; r < 4; r++)
      s[jt][r] = __builtin_fmaf(s[jt][r], scale, b2f(pv[r]));
  }
  float inv[4];
#pragma unroll
  for (int r = 0; r < 4; r++) {
    float m = s[0][r];
#pragma unroll
    for (int jt = 1; jt < 16; jt++) m = fmaxf(m, s[jt][r]);
    m = fmaxf(m, __shfl_xor(m, 1, 64));
    m = fmaxf(m, __shfl_xor(m, 2, 64));
    m = fmaxf(m, __shfl_xor(m, 4, 64));
    m = fmaxf(m, __shfl_xor(m, 8, 64));
    float rs = 0.f;
#pragma unroll
    for (int jt = 0; jt < 16; jt++) {
      float p = __expf(s[jt][r] - m);
      s[jt][r] = p;
      rs += p;
    }
    rs += __shfl_xor(rs, 1, 64);
    rs += __shfl_xor(rs, 2, 64);
    rs += __shfl_xor(rs, 4, 64);
    rs += __shfl_xor(rs, 8, 64);
    inv[r] = 1.f / rs;
  }
  __syncthreads();   // all waves done reading lsK before P overlays it
#pragma unroll
  for (int jt = 0; jt < 16; jt++)
#pragma unroll
    for (int r = 0; r < 4; r++)
      lsP[(w * 16 + q * 4 + r) * 264 + jt * 16 + c] = f2b(s[jt][r]);
  float4v o0 = zero4(), o1 = zero4();
#pragma unroll
  for (int kk = 0; kk < 8; kk++) {
    short8 ap = *(const short8*)&lsP[(w * 16 + c) * 264 + kk * 32 + q * 8];
    int sl0 = ((kk * 4 + q) ^ (c & 7)) * 8;
    short8 b0 = *(const short8*)&lsV[c * 256 + sl0];
    short8 b1 = *(const short8*)&lsV[(16 + c) * 256 + sl0];
    o0 = MFMA16(ap, b0, o0);
    o1 = MFMA16(ap, b1, o1);
  }
#pragma unroll
  for (int r = 0; r < 4; r++) {
    os[(n * 256 + i0 + q * 4 + r) * 256 + h * 32 + c]      = f2b(o0[r] * inv[r]);
    os[(n * 256 + i0 + q * 4 + r) * 256 + h * 32 + 16 + c] = f2b(o1[r] * inv[r]);
  }
}

// ============================================================================
// K4: out-proj + bias + residual + LayerNorm. 512 logical blocks, launched x2.
// ============================================================================
__global__ __launch_bounds__(256) void k4_out(
    const float* __restrict__ msa, const float* __restrict__ bo,
    const float* __restrict__ gamma, const float* __restrict__ beta,
    const char* __restrict__ ws, float* __restrict__ out)
{
  __shared__ __align__(16) short lsA[32 * 128];
  __shared__ __align__(16) short lsB[256 * 128];
  __shared__ float sred[2][32][2];       // [s1|s2][row-in-block][col-half]
  int bx = blockIdx.x, tid = threadIdx.x;
  if (bx >= 512) bx -= 512;             // duplicate half (instrumentation)
  int w = tid >> 6, l = tid & 63, q = l >> 4, c = l & 15;
  int rg = w >> 1, ch2 = w & 1;          // row-group (0/1), col-half (0/1)
  int R0 = bx * 32;                      // block's 32 rows
  int Rw = R0 + rg * 16;                 // this wave's 16 rows
  int C0 = ch2 * 128;                    // this wave's 128 cols
  const short* osrc = (const short*)(ws + O_OFF);
  const short* wto  = (const short*)(ws + WT_OFF) + 3 * 65536;

  float4v acc[8];
#pragma unroll
  for (int nt = 0; nt < 8; nt++) acc[nt] = zero4();

#pragma unroll 1
  for (int kk = 0; kk < 2; kk++) {
    if (kk) __syncthreads();
#pragma unroll
    for (int i = 0; i < 2; i++) {        // A: 32 rows x 128 k
      int ci = i * 256 + tid;
      int r = ci >> 4, pos = ci & 15;
      int kc = pos ^ (r & 7);
      ld_lds16(&osrc[(R0 + r) * 256 + kk * 128 + kc * 8], &lsA[ci * 8]);
    }
#pragma unroll
    for (int i = 0; i < 16; i++) {       // B: 256 ch x 128 k
      int ci = i * 256 + tid;
      int r = ci >> 4, pos = ci & 15;
      int kc = pos ^ (r & 7);
      ld_lds16(&wto[r * 256 + kk * 128 + kc * 8], &lsB[ci * 8]);
    }
    WAIT_VM0();
    __syncthreads();
#pragma unroll
    for (int ks = 0; ks < 4; ks++) {
      int rA = rg * 16 + c;
      int physA = (ks * 4 + q) ^ (rA & 7);
      short8 af = *(const short8*)&lsA[rA * 128 + physA * 8];
#pragma unroll
      for (int nt = 0; nt < 8; nt++) {
        int rB = C0 + nt * 16 + c;
        int phys = (ks * 4 + q) ^ (rB & 7);
        short8 bf = *(const short8*)&lsB[rB * 128 + phys * 8];
        acc[nt] = MFMA16(af, bf, acc[nt]);
      }
    }
  }

  // bias + residual + stats over this wave's 128 cols
  float s1[4] = {0, 0, 0, 0}, s2[4] = {0, 0, 0, 0};
#pragma unroll
  for (int nt = 0; nt < 8; nt++) {
    float bb = bo[C0 + nt * 16 + c];
#pragma unroll
    for (int r = 0; r < 4; r++) {
      float x = acc[nt][r] + bb + msa[(Rw + q * 4 + r) * 256 + C0 + nt * 16 + c];
      acc[nt][r] = x;
      s1[r] += x;
      s2[r] = __builtin_fmaf(x, x, s2[r]);
    }
  }
#pragma unroll
  for (int r = 0; r < 4; r++) {
    s1[r] += __shfl_xor(s1[r], 1, 64); s2[r] += __shfl_xor(s2[r], 1, 64);
    s1[r] += __shfl_xor(s1[r], 2, 64); s2[r] += __shfl_xor(s2[r], 2, 64);
    s1[r] += __shfl_xor(s1[r], 4, 64); s2[r] += __shfl_xor(s2[r], 4, 64);
    s1[r] += __shfl_xor(s1[r], 8, 64); s2[r] += __shfl_xor(s2[r], 8, 64);
  }
  if (c == 0) {
#pragma unroll
    for (int r = 0; r < 4; r++) {
      sred[0][rg * 16 + q * 4 + r][ch2] = s1[r];
      sred[1][rg * 16 + q * 4 + r][ch2] = s2[r];
    }
  }
  __syncthreads();
  float mu[4], rsd[4];
#pragma unroll
  for (int r = 0; r < 4; r++) {
    int row = rg * 16 + q * 4 + r;
    float a = sred[0][row][0] + sred[0][row][1];
    float b = sred[1][row][0] + sred[1][row][1];
    float m = a * (1.f / 256.f);
    float v = __builtin_fmaf(-m, m, b * (1.f / 256.f));
    mu[r] = m;
    rsd[r] = rsqrtf(v + 1e-5f);
  }
#pragma unroll
  for (int nt = 0; nt < 8; nt++) {
    float g = gamma[C0 + nt * 16 + c], bt = beta[C0 + nt * 16 + c];
#pragma unroll
    for (int r = 0; r < 4; r++)
      out[(Rw + q * 4 + r) * 256 + C0 + nt * 16 + c] =
          (acc[nt][r] - mu[r]) * rsd[r] * g + bt;
  }
}

extern "C" void kernel_launch(void* const* d_in, const int* in_sizes, int n_in,
                              void* d_out, int out_size, void* d_ws, size_t ws_size,
                              hipStream_t stream)
{
  const float* msa   = (const float*)d_in[0];
  const float* pair  = (const float*)d_in[1];
  const float* Wq    = (const float*)d_in[2];
  const float* bq    = (const float*)d_in[3];
  const float* Wk    = (const float*)d_in[4];
  const float* bk    = (const float*)d_in[5];
  const float* Wv    = (const float*)d_in[6];
  const float* bv    = (const float*)d_in[7];
  const float* Wpb   = (const float*)d_in[8];
  const float* bpb   = (const float*)d_in[9];
  const float* Wo    = (const float*)d_in[10];
  const float* bo    = (const float*)d_in[11];
  const float* gamma = (const float*)d_in[12];
  const float* beta  = (const float*)d_in[13];
  char* ws = (char*)d_ws;
  float* out = (float*)d_out;

  // INSTRUMENTATION: all grids x2 (idempotent duplicate work) so each kernel's
  // dispatch exceeds the 42us fillBuffer rows and appears in top-5 w/ counters.
  hipLaunchKernelGGL(k1_prep, dim3(1664), dim3(256), 0, stream,
                     msa, pair, Wq, Wk, Wv, Wpb, bpb, Wo, ws);
  hipLaunchKernelGGL(k2_qkv, dim3(1792), dim3(256), 0, stream,
                     bq, bk, bv, ws);
  hipLaunchKernelGGL(k3_attn, dim3(4096), dim3(256), 0, stream, ws);
  hipLaunchKernelGGL(k4_out, dim3(1024), dim3(256), 0, stream,
                     msa, bo, gamma, beta, ws, out);
}

// Round 7
// 157.963 us; speedup vs baseline: 1.2526x; 1.2526x over previous
//
#include <hip/hip_runtime.h>

// Problem constants
#define NSEQ 64
#define LL   256
#define DD   256
#define HH   8
#define HDIM 32

typedef short short8  __attribute__((ext_vector_type(8)));
typedef short short4v __attribute__((ext_vector_type(4)));
typedef float float4v __attribute__((ext_vector_type(4)));

#define MFMA16(a,b,c) __builtin_amdgcn_mfma_f32_16x16x32_bf16((a),(b),(c),0,0,0)

__device__ __forceinline__ float4v zero4() {
  float4v z;
  z[0] = 0.f; z[1] = 0.f; z[2] = 0.f; z[3] = 0.f;
  return z;
}

__device__ __forceinline__ short f2b(float f) {
  unsigned u = __float_as_uint(f);
  u = (u + 0x7fffu + ((u >> 16) & 1u)) >> 16;   // RNE
  return (short)u;
}

__device__ __forceinline__ float b2f(short s) {
  return __uint_as_float(((unsigned)(unsigned short)s) << 16);
}

// 2x f32 -> packed 2x bf16 (RNE), src0 in [15:0]
__device__ __forceinline__ unsigned pkbf(float a, float b) {
  unsigned r;
  asm volatile("v_cvt_pk_bf16_f32 %0, %1, %2" : "=v"(r) : "v"(a), "v"(b));
  return r;
}

// async global->LDS, 16B per lane. LDS dest must be wave-uniform-base + lane*16.
__device__ __forceinline__ void ld_lds16(const void* g, void* l) {
  __builtin_amdgcn_global_load_lds(
      (const __attribute__((address_space(1))) unsigned int*)g,
      (__attribute__((address_space(3))) unsigned int*)l, 16, 0, 0);
}
#define WAIT_VM0() __builtin_amdgcn_s_waitcnt(0x0F70)   // vmcnt(0) only

// ---- workspace layout (bytes); total ~34.5 MB (MSA16 and O share) ----
#define WT_OFF    0                            // 4 x 256x256 bf16 (Wq^T,Wk^T,Wv^T,Wo^T) [ch][k]
#define PB_OFF    (4*65536*2)                  // pb bf16 [h][i][j] (1MB) + fragments (1MB)
#define PBF_OFF   (PB_OFF + 8*65536*2)         // pb bf16 fragments [h][it][jt][lane][4] (transposed)
#define Q_OFF     (PB_OFF + 8*65536*4)         // per-head q_h[n][h][i][hd] bf16
#define K_OFF     (Q_OFF  + 16384*256*2)       // per-head k_h[n][h][j][hd] bf16
#define VT_OFF    (K_OFF  + 16384*256*2)       // [n][h][hd][j] bf16
#define MSA16_OFF (VT_OFF + 16384*256*2)       // 16384x256 bf16 (dead after k2)
#define O_OFF     MSA16_OFF                    // k3 output overlays MSA16

// ============================================================================
// K1: pb GEMM (256) + weight transpose via LDS (64) + msa->bf16 (512)
//     = 832 blocks. pb output is pre-multiplied by log2(e) for k3's exp2 path.
// ============================================================================
__global__ __launch_bounds__(256) void k1_prep(
    const float* __restrict__ msa,  const float* __restrict__ pair,
    const float* __restrict__ Wq,   const float* __restrict__ Wk,
    const float* __restrict__ Wv,   const float* __restrict__ Wpb,
    const float* __restrict__ bpb,  const float* __restrict__ Wo,
    char* __restrict__ ws)
{
  __shared__ __align__(16) short shm[4 * 64 * 128];   // 64KB: pair staging / transpose tile
  __shared__ short ldsWt[16 * 136];   // Wpb^T bf16, rows 8..15 zero, ld=136 (pad)
  int bx = blockIdx.x, tid = threadIdx.x;
  if (bx < 256) {
    short* pb16 = (short*)(ws + PB_OFF);
    for (int i = tid; i < 16 * 136; i += 256) ldsWt[i] = 0;
    __syncthreads();
    {
      float4 wv4 = *(const float4*)&Wpb[tid * 4];
      int kk = (tid * 4) >> 3, n0 = (tid * 4) & 7;
      ldsWt[(n0 + 0) * 136 + kk] = f2b(wv4.x);
      ldsWt[(n0 + 1) * 136 + kk] = f2b(wv4.y);
      ldsWt[(n0 + 2) * 136 + kk] = f2b(wv4.z);
      ldsWt[(n0 + 3) * 136 + kk] = f2b(wv4.w);
    }
    __syncthreads();
    int w = tid >> 6, l = tid & 63, q = l >> 4, c = l & 15;
    int base = bx * 256 + w * 64;          // block bx covers pair row i=bx, all j
    // stage pair[base .. base+64)[0..128) -> bf16 LDS, coalesced + swizzled
    short* lsWw = shm + w * 8192;
#pragma unroll
    for (int it = 0; it < 16; it++) {
      int jl = it * 4 + (l >> 4);
      int kc = l & 15;
      const float* src = &pair[(base + jl) * 128 + kc * 8];
      float4 a = *(const float4*)src;
      float4 b = *(const float4*)(src + 4);
      short8 v8;
      v8[0] = f2b(a.x); v8[1] = f2b(a.y); v8[2] = f2b(a.z); v8[3] = f2b(a.w);
      v8[4] = f2b(b.x); v8[5] = f2b(b.y); v8[6] = f2b(b.z); v8[7] = f2b(b.w);
      *(short8*)&lsWw[jl * 128 + ((kc ^ (jl & 7)) * 8)] = v8;
    }
    float bias = bpb[c & 7];
    short8 bf[4];
#pragma unroll
    for (int ks = 0; ks < 4; ks++)
      bf[ks] = *(const short8*)&ldsWt[c * 136 + ks * 32 + q * 8];
    float4v acc[4];
#pragma unroll
    for (int mt = 0; mt < 4; mt++) acc[mt] = zero4();
#pragma unroll
    for (int ks = 0; ks < 4; ks++) {
#pragma unroll
      for (int mt = 0; mt < 4; mt++) {
        int row = mt * 16 + c;
        short8 af = *(const short8*)&lsWw[row * 128 + (((ks * 4 + q) ^ (c & 7)) * 8)];
        acc[mt] = MFMA16(af, bf[ks], acc[mt]);
      }
    }
    if (c < 8) {
#pragma unroll
      for (int mt = 0; mt < 4; mt++) {
        short4v o;
#pragma unroll
        for (int r = 0; r < 4; r++)
          o[r] = f2b((acc[mt][r] + bias) * 1.44269504088896f);  // pre-x log2e
        *(short4v*)&pb16[c * 65536 + base + mt * 16 + q * 4] = o;
      }
    }
  } else if (bx < 320) {
    // weight transpose via LDS: 64 blocks, each a 64(k) x 64(n) tile
    int b2 = bx - 256;                  // 0..63
    int mat = b2 >> 4, sub = b2 & 15;
    int k0 = (sub >> 2) * 64, n0 = (sub & 3) * 64;
    const float* W = (mat == 0) ? Wq : (mat == 1) ? Wk : (mat == 2) ? Wv : Wo;
    short* wt = (short*)(ws + WT_OFF) + mat * 65536;
    short* ldsT = shm;                  // 64 x 72
#pragma unroll
    for (int p = 0; p < 4; p++) {
      int kl = p * 16 + (tid >> 4);
      int nl = (tid & 15) * 4;
      float4 v = *(const float4*)&W[(k0 + kl) * 256 + n0 + nl];
      ldsT[(nl + 0) * 72 + kl] = f2b(v.x);
      ldsT[(nl + 1) * 72 + kl] = f2b(v.y);
      ldsT[(nl + 2) * 72 + kl] = f2b(v.z);
      ldsT[(nl + 3) * 72 + kl] = f2b(v.w);
    }
    __syncthreads();
#pragma unroll
    for (int p = 0; p < 2; p++) {
      int id = p * 256 + tid;
      int nl = id >> 3, c8 = id & 7;
      *(short8*)&wt[(n0 + nl) * 256 + k0 + c8 * 8] =
          *(const short8*)&ldsT[nl * 72 + c8 * 8];
    }
  } else {
    // msa -> bf16 row-major
    int b3 = bx - 320;                  // 0..511, 32 rows each
    const float* src = msa + b3 * 8192;
    short* dst = (short*)(ws + MSA16_OFF) + b3 * 8192;
#pragma unroll
    for (int i = 0; i < 8; i++) {
      int idx = i * 1024 + tid * 4;
      float4 v = *(const float4*)&src[idx];
      short4v s;
      s[0] = f2b(v.x); s[1] = f2b(v.y); s[2] = f2b(v.z); s[3] = f2b(v.w);
      *(short4v*)&dst[idx] = s;
    }
  }
}

// ============================================================================
// K2: QKV GEMM (768 blocks) + pb fragment repack (128 blocks) = 896 blocks.
// Repack now emits TRANSPOSED fragments for k3's swapped-QK layout:
// pbf[h][it][jt][lane][r] = pb[h][i0+c][jt*16+q*4+r]  (vectorized copy).
// ============================================================================
__global__ __launch_bounds__(256) void k2_qkv(
    const float* __restrict__ bq, const float* __restrict__ bk,
    const float* __restrict__ bv, char* __restrict__ ws)
{
  __shared__ __align__(16) short ls[2 * 128 * 128];   // lsA | lsB, reused as lsC
  short* lsA = ls;
  short* lsB = ls + 16384;
  int bx = blockIdx.x, tid = threadIdx.x;
  if (bx >= 768) {
    // pb repack: pb16[h][i][j] -> transposed fragments
    int b = bx - 768;                   // 0..127
    int it16 = b & 15;
    const short* src = (const short*)(ws + PB_OFF) + (b >> 4) * 65536 + it16 * 4096;
    short* pbf = (short*)(ws + PBF_OFF);
    short* lt = lsA;                    // 16 x 264
#pragma unroll
    for (int i2 = 0; i2 < 2; i2++) {
      int idx = i2 * 2048 + tid * 8;
      *(short8*)&lt[(idx >> 8) * 264 + (idx & 255)] = *(const short8*)&src[idx];
    }
    __syncthreads();
#pragma unroll
    for (int i2 = 0; i2 < 4; i2++) {
      int fid = i2 * 256 + tid;
      int jt = fid >> 6, lane = fid & 63;
      int qp = lane >> 4, cp = lane & 15;
      short4v v = *(const short4v*)&lt[cp * 264 + jt * 16 + qp * 4];
      *(short4v*)&pbf[((b * 16 + jt) * 64 + lane) * 4] = v;
    }
    return;
  }
  int rt = bx & 127, ct = bx >> 7;       // row-tile, col-tile
  int m = ct >> 1, cb = (ct & 1) * 128;  // matrix, ch base within matrix
  int R0 = rt * 128;
  const short* msa16 = (const short*)(ws + MSA16_OFF);
  const short* wt = (const short*)(ws + WT_OFF) + m * 65536;
  int w = tid >> 6, l = tid & 63, q = l >> 4, c = l & 15;
  int WR = (w & 1) * 64, WC = (w >> 1) * 64;
  float4v acc[4][4];
#pragma unroll
  for (int mt = 0; mt < 4; mt++)
#pragma unroll
    for (int nt = 0; nt < 4; nt++) acc[mt][nt] = zero4();

#pragma unroll 1
  for (int kk = 0; kk < 2; kk++) {
    if (kk) __syncthreads();
#pragma unroll
    for (int i = 0; i < 8; i++) {
      int ci = i * 256 + tid;
      int r = ci >> 4, pos = ci & 15;
      int kc = pos ^ (r & 7);
      ld_lds16(&msa16[(R0 + r) * 256 + kk * 128 + kc * 8], &lsA[ci * 8]);
    }
#pragma unroll
    for (int i = 0; i < 8; i++) {
      int ci = i * 256 + tid;
      int r = ci >> 4, pos = ci & 15;
      int kc = pos ^ (r & 7);
      ld_lds16(&wt[(cb + r) * 256 + kk * 128 + kc * 8], &lsB[ci * 8]);
    }
    WAIT_VM0();
    __syncthreads();
#pragma unroll
    for (int ks = 0; ks < 4; ks++) {
      short8 af[4], bf[4];
#pragma unroll
      for (int mt = 0; mt < 4; mt++) {
        int r = WR + mt * 16 + c;
        int phys = (ks * 4 + q) ^ (r & 7);
        af[mt] = *(const short8*)&lsA[r * 128 + phys * 8];
      }
#pragma unroll
      for (int nt = 0; nt < 4; nt++) {
        int r = WC + nt * 16 + c;
        int phys = (ks * 4 + q) ^ (r & 7);
        bf[nt] = *(const short8*)&lsB[r * 128 + phys * 8];
      }
#pragma unroll
      for (int mt = 0; mt < 4; mt++)
#pragma unroll
        for (int nt = 0; nt < 4; nt++)
          acc[mt][nt] = MFMA16(af[mt], bf[nt], acc[mt][nt]);
    }
  }

  const float* bp = (m == 0) ? bq : (m == 1) ? bk : bv;
  int n = R0 >> 8;
  __syncthreads();                      // all waves done reading lsA/lsB
  short* lsC = ls;                      // 128 x 136 bf16
  if (m < 2) {
    // lsC[i][ch] then coalesced per-head-packed store dst[n][h][i][hd]
#pragma unroll
    for (int nt = 0; nt < 4; nt++) {
      float bb = bp[cb + WC + nt * 16 + c];
#pragma unroll
      for (int mt = 0; mt < 4; mt++)
#pragma unroll
        for (int r = 0; r < 4; r++)
          lsC[(WR + mt * 16 + q * 4 + r) * 136 + WC + nt * 16 + c] =
              f2b(acc[mt][nt][r] + bb);
    }
    __syncthreads();
    short* dst = (short*)(ws + (m == 0 ? Q_OFF : K_OFF)) + n * 65536;
    int ibase = R0 & 255;
#pragma unroll
    for (int p = 0; p < 8; p++) {
      int id = p * 256 + tid;
      int il = id >> 4, ch8 = id & 15;
      int chg = cb + ch8 * 8;
      int hh = chg >> 5, hd0 = chg & 31;
      *(short8*)&dst[(hh * 256 + ibase + il) * 32 + hd0] =
          *(const short8*)&lsC[il * 136 + ch8 * 8];
    }
  } else {
    // lsC[ch][j] then coalesced store vt[n*256+ch][j]
#pragma unroll
    for (int nt = 0; nt < 4; nt++) {
      float bb = bp[cb + WC + nt * 16 + c];
#pragma unroll
      for (int mt = 0; mt < 4; mt++)
#pragma unroll
        for (int r = 0; r < 4; r++)
          lsC[(WC + nt * 16 + c) * 136 + WR + mt * 16 + q * 4 + r] =
              f2b(acc[mt][nt][r] + bb);
    }
    __syncthreads();
    short* vt = (short*)(ws + VT_OFF) + n * 65536;
    int jbase = R0 & 255;
#pragma unroll
    for (int p = 0; p < 8; p++) {
      int id = p * 256 + tid;
      int chl = id >> 4, j8 = id & 15;
      int chg = cb + chl;
      *(short8*)&vt[chg * 256 + jbase + j8 * 8] =
          *(const short8*)&lsC[chl * 136 + j8 * 8];
    }
  }
}

// ============================================================================
// K3: attention, swapped-QK layout. s = mfma(K,Q) -> lane (q,c) holds 64
// j-values of query i0+c -> in-register softmax (2 shfls), vectorized b64 P
// writes via v_cvt_pk_bf16_f32, PV = mfma(V,P) -> O^T frag, short4v stores.
// exp2 path (scale & pb pre-x log2e). K/V staged per block; P overlays K.
// ============================================================================
__global__ __launch_bounds__(256) void k3_attn(char* __restrict__ ws)
{
  __shared__ __align__(16) short lds[25088];   // 50176 B
  short* lsK = lds;
  short* lsP = lds;
  short* lsV = lds + 16896;
  int bx = blockIdx.x, tid = threadIdx.x;
  int qq = bx >> 9, grp = bx & 511;
  int n = grp >> 3, h = grp & 7;
  int w = tid >> 6, l = tid & 63, q = l >> 4, c = l & 15;
  const short* qh = (const short*)(ws + Q_OFF) + (n * HH + h) * 256 * HDIM;
  const short* kh = (const short*)(ws + K_OFF) + (n * HH + h) * 256 * HDIM;
  const short* vt = (const short*)(ws + VT_OFF) + (n * HH + h) * HDIM * 256;
  const short* pbf = (const short*)(ws + PBF_OFF) + (h * 16 + qq * 4 + w) * 16 * 256;
  short* os = (short*)(ws + O_OFF);
  const float scl2 = 0.17677669529663687f * 1.44269504088896f;  // 1/sqrt(32)*log2e
  int i0 = qq * 64 + w * 16;             // this wave's 16 query rows

  short8 aq = *(const short8*)&qh[(i0 + c) * HDIM + q * 8];

#pragma unroll
  for (int i = 0; i < 4; i++) {
    int ci = i * 256 + tid;
    ld_lds16(&kh[ci * 8], &lsK[ci * 8]);
  }
#pragma unroll
  for (int i = 0; i < 4; i++) {
    int ci = i * 256 + tid;
    int row = ci >> 5, j = ci & 31;
    int sj = j ^ (row & 7);
    ld_lds16(&vt[row * 256 + sj * 8], &lsV[ci * 8]);
  }
  WAIT_VM0();
  __syncthreads();

  // swapped QK^T: s[jt][r] = S[j = jt*16+q*4+r][i0+c] * (un-scaled)
  float4v s[16];
#pragma unroll
  for (int jt = 0; jt < 16; jt++) {
    short8 kf = *(const short8*)&lsK[(jt * 16 + c) * 32 + q * 8];
    s[jt] = MFMA16(kf, aq, zero4());
  }
  // scale(+log2e) + pair bias (pre-x log2e, transposed fragments)
#pragma unroll
  for (int jt = 0; jt < 16; jt++) {
    short4v pv = *(const short4v*)&pbf[(jt * 64 + l) * 4];
#pragma unroll
    for (int r = 0; r < 4; r++)
      s[jt][r] = __builtin_fmaf(s[jt][r], scl2, b2f(pv[r]));
  }
  // scalar softmax for query i0+c: in-reg trees + 2 shfls
  float t[16];
#pragma unroll
  for (int jt = 0; jt < 16; jt++)
    t[jt] = fmaxf(fmaxf(s[jt][0], s[jt][1]), fmaxf(s[jt][2], s[jt][3]));
#pragma unroll
  for (int st = 8; st >= 1; st >>= 1)
#pragma unroll
    for (int i = 0; i < st; i++) t[i] = fmaxf(t[i], t[i + st]);
  float m = fmaxf(t[0], __shfl_xor(t[0], 16, 64));
  m = fmaxf(m, __shfl_xor(m, 32, 64));
#pragma unroll
  for (int jt = 0; jt < 16; jt++) {
#pragma unroll
    for (int r = 0; r < 4; r++) s[jt][r] = exp2f(s[jt][r] - m);
    t[jt] = (s[jt][0] + s[jt][1]) + (s[jt][2] + s[jt][3]);
  }
#pragma unroll
  for (int st = 8; st >= 1; st >>= 1)
#pragma unroll
    for (int i = 0; i < st; i++) t[i] += t[i + st];
  float rs = t[0];
  rs += __shfl_xor(rs, 16, 64);
  rs += __shfl_xor(rs, 32, 64);
  float inv = 1.f / rs;

  __syncthreads();   // all waves done reading lsK before P overlays it
  // P -> LDS bf16, vectorized: row i (wave-local c), cols jt*16+q*4..+3
  int prow = (w * 16 + c) * 264;
#pragma unroll
  for (int jt = 0; jt < 16; jt++) {
    uint2 u;
    u.x = pkbf(s[jt][0], s[jt][1]);
    u.y = pkbf(s[jt][2], s[jt][3]);
    *(uint2*)&lsP[prow + jt * 16 + q * 4] = u;
  }
  // PV: O^T = V^T-frag x P-frag
  float4v o0 = zero4(), o1 = zero4();
#pragma unroll
  for (int kk = 0; kk < 8; kk++) {
    short8 pf = *(const short8*)&lsP[prow + kk * 32 + q * 8];
    int sl0 = ((kk * 4 + q) ^ (c & 7)) * 8;
    short8 b0 = *(const short8*)&lsV[c * 256 + sl0];
    short8 b1 = *(const short8*)&lsV[(16 + c) * 256 + sl0];
    o0 = MFMA16(b0, pf, o0);
    o1 = MFMA16(b1, pf, o1);
  }
  // lane (q,c): O[i0+c][d = q*4+r] (o0) and [d = 16+q*4+r] (o1)
  short* orow = &os[(n * 256 + i0 + c) * 256 + h * 32];
  short4v t0, t1;
#pragma unroll
  for (int r = 0; r < 4; r++) {
    t0[r] = f2b(o0[r] * inv);
    t1[r] = f2b(o1[r] * inv);
  }
  *(short4v*)&orow[q * 4] = t0;
  *(short4v*)&orow[16 + q * 4] = t1;
}

// ============================================================================
// K4: out-proj + bias + residual + LayerNorm. LDS-staged, 32 rows/block:
// grid 512, 2 blocks/CU.
// ============================================================================
__global__ __launch_bounds__(256) void k4_out(
    const float* __restrict__ msa, const float* __restrict__ bo,
    const float* __restrict__ gamma, const float* __restrict__ beta,
    const char* __restrict__ ws, float* __restrict__ out)
{
  __shared__ __align__(16) short lsA[32 * 128];
  __shared__ __align__(16) short lsB[256 * 128];
  __shared__ float sred[2][32][2];       // [s1|s2][row-in-block][col-half]
  int bx = blockIdx.x, tid = threadIdx.x;
  int w = tid >> 6, l = tid & 63, q = l >> 4, c = l & 15;
  int rg = w >> 1, ch2 = w & 1;          // row-group (0/1), col-half (0/1)
  int R0 = bx * 32;                      // block's 32 rows
  int Rw = R0 + rg * 16;                 // this wave's 16 rows
  int C0 = ch2 * 128;                    // this wave's 128 cols
  const short* osrc = (const short*)(ws + O_OFF);
  const short* wto  = (const short*)(ws + WT_OFF) + 3 * 65536;

  float4v acc[8];
#pragma unroll
  for (int nt = 0; nt < 8; nt++) acc[nt] = zero4();

#pragma unroll 1
  for (int kk = 0; kk < 2; kk++) {
    if (kk) __syncthreads();
#pragma unroll
    for (int i = 0; i < 2; i++) {        // A: 32 rows x 128 k
      int ci = i * 256 + tid;
      int r = ci >> 4, pos = ci & 15;
      int kc = pos ^ (r & 7);
      ld_lds16(&osrc[(R0 + r) * 256 + kk * 128 + kc * 8], &lsA[ci * 8]);
    }
#pragma unroll
    for (int i = 0; i < 16; i++) {       // B: 256 ch x 128 k
      int ci = i * 256 + tid;
      int r = ci >> 4, pos = ci & 15;
      int kc = pos ^ (r & 7);
      ld_lds16(&wto[r * 256 + kk * 128 + kc * 8], &lsB[ci * 8]);
    }
    WAIT_VM0();
    __syncthreads();
#pragma unroll
    for (int ks = 0; ks < 4; ks++) {
      int rA = rg * 16 + c;
      int physA = (ks * 4 + q) ^ (rA & 7);
      short8 af = *(const short8*)&lsA[rA * 128 + physA * 8];
#pragma unroll
      for (int nt = 0; nt < 8; nt++) {
        int rB = C0 + nt * 16 + c;
        int phys = (ks * 4 + q) ^ (rB & 7);
        short8 bf = *(const short8*)&lsB[rB * 128 + phys * 8];
        acc[nt] = MFMA16(af, bf, acc[nt]);
      }
    }
  }

  // bias + residual + stats over this wave's 128 cols
  float s1[4] = {0, 0, 0, 0}, s2[4] = {0, 0, 0, 0};
#pragma unroll
  for (int nt = 0; nt < 8; nt++) {
    float bb = bo[C0 + nt * 16 + c];
#pragma unroll
    for (int r = 0; r < 4; r++) {
      float x = acc[nt][r] + bb + msa[(Rw + q * 4 + r) * 256 + C0 + nt * 16 + c];
      acc[nt][r] = x;
      s1[r] += x;
      s2[r] = __builtin_fmaf(x, x, s2[r]);
    }
  }
#pragma unroll
  for (int r = 0; r < 4; r++) {
    s1[r] += __shfl_xor(s1[r], 1, 64); s2[r] += __shfl_xor(s2[r], 1, 64);
    s1[r] += __shfl_xor(s1[r], 2, 64); s2[r] += __shfl_xor(s2[r], 2, 64);
    s1[r] += __shfl_xor(s1[r], 4, 64); s2[r] += __shfl_xor(s2[r], 4, 64);
    s1[r] += __shfl_xor(s1[r], 8, 64); s2[r] += __shfl_xor(s2[r], 8, 64);
  }
  if (c == 0) {
#pragma unroll
    for (int r = 0; r < 4; r++) {
      sred[0][rg * 16 + q * 4 + r][ch2] = s1[r];
      sred[1][rg * 16 + q * 4 + r][ch2] = s2[r];
    }
  }
  __syncthreads();
  float mu[4], rsd[4];
#pragma unroll
  for (int r = 0; r < 4; r++) {
    int row = rg * 16 + q * 4 + r;
    float a = sred[0][row][0] + sred[0][row][1];
    float b = sred[1][row][0] + sred[1][row][1];
    float m = a * (1.f / 256.f);
    float v = __builtin_fmaf(-m, m, b * (1.f / 256.f));
    mu[r] = m;
    rsd[r] = rsqrtf(v + 1e-5f);
  }
#pragma unroll
  for (int nt = 0; nt < 8; nt++) {
    float g = gamma[C0 + nt * 16 + c], bt = beta[C0 + nt * 16 + c];
#pragma unroll
    for (int r = 0; r < 4; r++)
      out[(Rw + q * 4 + r) * 256 + C0 + nt * 16 + c] =
          (acc[nt][r] - mu[r]) * rsd[r] * g + bt;
  }
}

extern "C" void kernel_launch(void* const* d_in, const int* in_sizes, int n_in,
                              void* d_out, int out_size, void* d_ws, size_t ws_size,
                              hipStream_t stream)
{
  const float* msa   = (const float*)d_in[0];
  const float* pair  = (const float*)d_in[1];
  const float* Wq    = (const float*)d_in[2];
  const float* bq    = (const float*)d_in[3];
  const float* Wk    = (const float*)d_in[4];
  const float* bk    = (const float*)d_in[5];
  const float* Wv    = (const float*)d_in[6];
  const float* bv    = (const float*)d_in[7];
  const float* Wpb   = (const float*)d_in[8];
  const float* bpb   = (const float*)d_in[9];
  const float* Wo    = (const float*)d_in[10];
  const float* bo    = (const float*)d_in[11];
  const float* gamma = (const float*)d_in[12];
  const float* beta  = (const float*)d_in[13];
  char* ws = (char*)d_ws;
  float* out = (float*)d_out;

  hipLaunchKernelGGL(k1_prep, dim3(832), dim3(256), 0, stream,
                     msa, pair, Wq, Wk, Wv, Wpb, bpb, Wo, ws);
  hipLaunchKernelGGL(k2_qkv, dim3(896), dim3(256), 0, stream,
                     bq, bk, bv, ws);
  hipLaunchKernelGGL(k3_attn, dim3(2048), dim3(256), 0, stream, ws);
  hipLaunchKernelGGL(k4_out, dim3(512), dim3(256), 0, stream,
                     msa, bo, gamma, beta, ws, out);
}

// Round 8
// 155.604 us; speedup vs baseline: 1.2716x; 1.0152x over previous
//
#include <hip/hip_runtime.h>

// Problem constants
#define NSEQ 64
#define LL   256
#define DD   256
#define HH   8
#define HDIM 32

typedef short short8  __attribute__((ext_vector_type(8)));
typedef short short4v __attribute__((ext_vector_type(4)));
typedef float float4v __attribute__((ext_vector_type(4)));

#define MFMA16(a,b,c) __builtin_amdgcn_mfma_f32_16x16x32_bf16((a),(b),(c),0,0,0)

__device__ __forceinline__ float4v zero4() {
  float4v z;
  z[0] = 0.f; z[1] = 0.f; z[2] = 0.f; z[3] = 0.f;
  return z;
}

__device__ __forceinline__ short f2b(float f) {
  unsigned u = __float_as_uint(f);
  u = (u + 0x7fffu + ((u >> 16) & 1u)) >> 16;   // RNE
  return (short)u;
}

__device__ __forceinline__ float b2f(short s) {
  return __uint_as_float(((unsigned)(unsigned short)s) << 16);
}

// 2x f32 -> packed 2x bf16 (RNE), src0 in [15:0]
__device__ __forceinline__ unsigned pkbf(float a, float b) {
  unsigned r;
  asm volatile("v_cvt_pk_bf16_f32 %0, %1, %2" : "=v"(r) : "v"(a), "v"(b));
  return r;
}

// async global->LDS, 16B per lane. LDS dest must be wave-uniform-base + lane*16.
__device__ __forceinline__ void ld_lds16(const void* g, void* l) {
  __builtin_amdgcn_global_load_lds(
      (const __attribute__((address_space(1))) unsigned int*)g,
      (__attribute__((address_space(3))) unsigned int*)l, 16, 0, 0);
}
#define WAIT_VM0() __builtin_amdgcn_s_waitcnt(0x0F70)   // vmcnt(0) only

// ---- workspace layout (bytes); total ~34.5 MB (MSA16 and O share) ----
#define WT_OFF    0                            // 4 x 256x256 bf16 (Wq^T,Wk^T,Wv^T,Wo^T) [ch][k]
#define PB_OFF    (4*65536*2)                  // pb bf16 [h][i][j] (1MB) + fragments (1MB)
#define PBF_OFF   (PB_OFF + 8*65536*2)         // pb bf16 fragments [h][it][jt][lane][4] (transposed)
#define Q_OFF     (PB_OFF + 8*65536*4)         // per-head q_h[n][h][i][hd] bf16
#define K_OFF     (Q_OFF  + 16384*256*2)       // per-head k_h[n][h][j][hd] bf16
#define VT_OFF    (K_OFF  + 16384*256*2)       // [n][h][hd][j] bf16
#define MSA16_OFF (VT_OFF + 16384*256*2)       // 16384x256 bf16 (dead after k2)
#define O_OFF     MSA16_OFF                    // k3 output overlays MSA16

// ============================================================================
// K1: pb GEMM (256) + weight transpose via LDS (64) + msa->bf16 (512)
//     = 832 blocks. pb output is pre-multiplied by log2(e) for k3's exp2 path.
// ============================================================================
__global__ __launch_bounds__(256) void k1_prep(
    const float* __restrict__ msa,  const float* __restrict__ pair,
    const float* __restrict__ Wq,   const float* __restrict__ Wk,
    const float* __restrict__ Wv,   const float* __restrict__ Wpb,
    const float* __restrict__ bpb,  const float* __restrict__ Wo,
    char* __restrict__ ws)
{
  __shared__ __align__(16) short shm[4 * 64 * 128];   // 64KB: pair staging / transpose tile
  __shared__ short ldsWt[16 * 136];   // Wpb^T bf16, rows 8..15 zero, ld=136 (pad)
  int bx = blockIdx.x, tid = threadIdx.x;
  if (bx < 256) {
    short* pb16 = (short*)(ws + PB_OFF);
    for (int i = tid; i < 16 * 136; i += 256) ldsWt[i] = 0;
    __syncthreads();
    {
      float4 wv4 = *(const float4*)&Wpb[tid * 4];
      int kk = (tid * 4) >> 3, n0 = (tid * 4) & 7;
      ldsWt[(n0 + 0) * 136 + kk] = f2b(wv4.x);
      ldsWt[(n0 + 1) * 136 + kk] = f2b(wv4.y);
      ldsWt[(n0 + 2) * 136 + kk] = f2b(wv4.z);
      ldsWt[(n0 + 3) * 136 + kk] = f2b(wv4.w);
    }
    __syncthreads();
    int w = tid >> 6, l = tid & 63, q = l >> 4, c = l & 15;
    int base = bx * 256 + w * 64;          // block bx covers pair row i=bx, all j
    // stage pair[base .. base+64)[0..128) -> bf16 LDS, coalesced + swizzled
    short* lsWw = shm + w * 8192;
#pragma unroll
    for (int it = 0; it < 16; it++) {
      int jl = it * 4 + (l >> 4);
      int kc = l & 15;
      const float* src = &pair[(base + jl) * 128 + kc * 8];
      float4 a = *(const float4*)src;
      float4 b = *(const float4*)(src + 4);
      short8 v8;
      v8[0] = f2b(a.x); v8[1] = f2b(a.y); v8[2] = f2b(a.z); v8[3] = f2b(a.w);
      v8[4] = f2b(b.x); v8[5] = f2b(b.y); v8[6] = f2b(b.z); v8[7] = f2b(b.w);
      *(short8*)&lsWw[jl * 128 + ((kc ^ (jl & 7)) * 8)] = v8;
    }
    float bias = bpb[c & 7];
    short8 bf[4];
#pragma unroll
    for (int ks = 0; ks < 4; ks++)
      bf[ks] = *(const short8*)&ldsWt[c * 136 + ks * 32 + q * 8];
    float4v acc[4];
#pragma unroll
    for (int mt = 0; mt < 4; mt++) acc[mt] = zero4();
#pragma unroll
    for (int ks = 0; ks < 4; ks++) {
#pragma unroll
      for (int mt = 0; mt < 4; mt++) {
        int row = mt * 16 + c;
        short8 af = *(const short8*)&lsWw[row * 128 + (((ks * 4 + q) ^ (c & 7)) * 8)];
        acc[mt] = MFMA16(af, bf[ks], acc[mt]);
      }
    }
    if (c < 8) {
#pragma unroll
      for (int mt = 0; mt < 4; mt++) {
        short4v o;
#pragma unroll
        for (int r = 0; r < 4; r++)
          o[r] = f2b((acc[mt][r] + bias) * 1.44269504088896f);  // pre-x log2e
        *(short4v*)&pb16[c * 65536 + base + mt * 16 + q * 4] = o;
      }
    }
  } else if (bx < 320) {
    // weight transpose via LDS: 64 blocks, each a 64(k) x 64(n) tile
    int b2 = bx - 256;                  // 0..63
    int mat = b2 >> 4, sub = b2 & 15;
    int k0 = (sub >> 2) * 64, n0 = (sub & 3) * 64;
    const float* W = (mat == 0) ? Wq : (mat == 1) ? Wk : (mat == 2) ? Wv : Wo;
    short* wt = (short*)(ws + WT_OFF) + mat * 65536;
    short* ldsT = shm;                  // 64 x 72
#pragma unroll
    for (int p = 0; p < 4; p++) {
      int kl = p * 16 + (tid >> 4);
      int nl = (tid & 15) * 4;
      float4 v = *(const float4*)&W[(k0 + kl) * 256 + n0 + nl];
      ldsT[(nl + 0) * 72 + kl] = f2b(v.x);
      ldsT[(nl + 1) * 72 + kl] = f2b(v.y);
      ldsT[(nl + 2) * 72 + kl] = f2b(v.z);
      ldsT[(nl + 3) * 72 + kl] = f2b(v.w);
    }
    __syncthreads();
#pragma unroll
    for (int p = 0; p < 2; p++) {
      int id = p * 256 + tid;
      int nl = id >> 3, c8 = id & 7;
      *(short8*)&wt[(n0 + nl) * 256 + k0 + c8 * 8] =
          *(const short8*)&ldsT[nl * 72 + c8 * 8];
    }
  } else {
    // msa -> bf16 row-major
    int b3 = bx - 320;                  // 0..511, 32 rows each
    const float* src = msa + b3 * 8192;
    short* dst = (short*)(ws + MSA16_OFF) + b3 * 8192;
#pragma unroll
    for (int i = 0; i < 8; i++) {
      int idx = i * 1024 + tid * 4;
      float4 v = *(const float4*)&src[idx];
      short4v s;
      s[0] = f2b(v.x); s[1] = f2b(v.y); s[2] = f2b(v.z); s[3] = f2b(v.w);
      *(short4v*)&dst[idx] = s;
    }
  }
}

// ============================================================================
// K2: QKV GEMM (768 blocks) + pb fragment repack (128 blocks) = 896 blocks.
// Repack emits TRANSPOSED fragments for k3's swapped-QK layout:
// pbf[h][it][jt][lane][r] = pb[h][i0+c][jt*16+q*4+r]  (vectorized copy).
// ============================================================================
__global__ __launch_bounds__(256) void k2_qkv(
    const float* __restrict__ bq, const float* __restrict__ bk,
    const float* __restrict__ bv, char* __restrict__ ws)
{
  __shared__ __align__(16) short ls[2 * 128 * 128];   // lsA | lsB, reused as lsC
  short* lsA = ls;
  short* lsB = ls + 16384;
  int bx = blockIdx.x, tid = threadIdx.x;
  if (bx >= 768) {
    // pb repack: pb16[h][i][j] -> transposed fragments
    int b = bx - 768;                   // 0..127
    int it16 = b & 15;
    const short* src = (const short*)(ws + PB_OFF) + (b >> 4) * 65536 + it16 * 4096;
    short* pbf = (short*)(ws + PBF_OFF);
    short* lt = lsA;                    // 16 x 264
#pragma unroll
    for (int i2 = 0; i2 < 2; i2++) {
      int idx = i2 * 2048 + tid * 8;
      *(short8*)&lt[(idx >> 8) * 264 + (idx & 255)] = *(const short8*)&src[idx];
    }
    __syncthreads();
#pragma unroll
    for (int i2 = 0; i2 < 4; i2++) {
      int fid = i2 * 256 + tid;
      int jt = fid >> 6, lane = fid & 63;
      int qp = lane >> 4, cp = lane & 15;
      short4v v = *(const short4v*)&lt[cp * 264 + jt * 16 + qp * 4];
      *(short4v*)&pbf[((b * 16 + jt) * 64 + lane) * 4] = v;
    }
    return;
  }
  int rt = bx & 127, ct = bx >> 7;       // row-tile, col-tile
  int m = ct >> 1, cb = (ct & 1) * 128;  // matrix, ch base within matrix
  int R0 = rt * 128;
  const short* msa16 = (const short*)(ws + MSA16_OFF);
  const short* wt = (const short*)(ws + WT_OFF) + m * 65536;
  int w = tid >> 6, l = tid & 63, q = l >> 4, c = l & 15;
  int WR = (w & 1) * 64, WC = (w >> 1) * 64;
  float4v acc[4][4];
#pragma unroll
  for (int mt = 0; mt < 4; mt++)
#pragma unroll
    for (int nt = 0; nt < 4; nt++) acc[mt][nt] = zero4();

#pragma unroll 1
  for (int kk = 0; kk < 2; kk++) {
    if (kk) __syncthreads();
#pragma unroll
    for (int i = 0; i < 8; i++) {
      int ci = i * 256 + tid;
      int r = ci >> 4, pos = ci & 15;
      int kc = pos ^ (r & 7);
      ld_lds16(&msa16[(R0 + r) * 256 + kk * 128 + kc * 8], &lsA[ci * 8]);
    }
#pragma unroll
    for (int i = 0; i < 8; i++) {
      int ci = i * 256 + tid;
      int r = ci >> 4, pos = ci & 15;
      int kc = pos ^ (r & 7);
      ld_lds16(&wt[(cb + r) * 256 + kk * 128 + kc * 8], &lsB[ci * 8]);
    }
    WAIT_VM0();
    __syncthreads();
#pragma unroll
    for (int ks = 0; ks < 4; ks++) {
      short8 af[4], bf[4];
#pragma unroll
      for (int mt = 0; mt < 4; mt++) {
        int r = WR + mt * 16 + c;
        int phys = (ks * 4 + q) ^ (r & 7);
        af[mt] = *(const short8*)&lsA[r * 128 + phys * 8];
      }
#pragma unroll
      for (int nt = 0; nt < 4; nt++) {
        int r = WC + nt * 16 + c;
        int phys = (ks * 4 + q) ^ (r & 7);
        bf[nt] = *(const short8*)&lsB[r * 128 + phys * 8];
      }
#pragma unroll
      for (int mt = 0; mt < 4; mt++)
#pragma unroll
        for (int nt = 0; nt < 4; nt++)
          acc[mt][nt] = MFMA16(af[mt], bf[nt], acc[mt][nt]);
    }
  }

  const float* bp = (m == 0) ? bq : (m == 1) ? bk : bv;
  int n = R0 >> 8;
  __syncthreads();                      // all waves done reading lsA/lsB
  short* lsC = ls;                      // 128 x 136 bf16
  if (m < 2) {
    // lsC[i][ch] then coalesced per-head-packed store dst[n][h][i][hd]
#pragma unroll
    for (int nt = 0; nt < 4; nt++) {
      float bb = bp[cb + WC + nt * 16 + c];
#pragma unroll
      for (int mt = 0; mt < 4; mt++)
#pragma unroll
        for (int r = 0; r < 4; r++)
          lsC[(WR + mt * 16 + q * 4 + r) * 136 + WC + nt * 16 + c] =
              f2b(acc[mt][nt][r] + bb);
    }
    __syncthreads();
    short* dst = (short*)(ws + (m == 0 ? Q_OFF : K_OFF)) + n * 65536;
    int ibase = R0 & 255;
#pragma unroll
    for (int p = 0; p < 8; p++) {
      int id = p * 256 + tid;
      int il = id >> 4, ch8 = id & 15;
      int chg = cb + ch8 * 8;
      int hh = chg >> 5, hd0 = chg & 31;
      *(short8*)&dst[(hh * 256 + ibase + il) * 32 + hd0] =
          *(const short8*)&lsC[il * 136 + ch8 * 8];
    }
  } else {
    // lsC[ch][j] then coalesced store vt[n*256+ch][j]
#pragma unroll
    for (int nt = 0; nt < 4; nt++) {
      float bb = bp[cb + WC + nt * 16 + c];
#pragma unroll
      for (int mt = 0; mt < 4; mt++)
#pragma unroll
        for (int r = 0; r < 4; r++)
          lsC[(WC + nt * 16 + c) * 136 + WR + mt * 16 + q * 4 + r] =
              f2b(acc[mt][nt][r] + bb);
    }
    __syncthreads();
    short* vt = (short*)(ws + VT_OFF) + n * 65536;
    int jbase = R0 & 255;
#pragma unroll
    for (int p = 0; p < 8; p++) {
      int id = p * 256 + tid;
      int chl = id >> 4, j8 = id & 15;
      int chg = cb + chl;
      *(short8*)&vt[chg * 256 + jbase + j8 * 8] =
          *(const short8*)&lsC[chl * 136 + j8 * 8];
    }
  }
}

// ============================================================================
// K3: attention, swapped-QK layout. LDS DIET: P is per-wave 16x136 used in
// TWO half-passes (write jt 0..7 -> PV kk 0..3 -> overwrite jt 8..15 -> PV
// kk 4..7), wave-private so no extra barriers. P overlays K. LDS total
// 33792 B (was 50176) -> 4 blocks/CU (was 3), 16 waves/CU. pbf fragment
// loads hoisted before the staging drain so their L2 latency hides there.
// ============================================================================
__global__ __launch_bounds__(256, 4) void k3_attn(char* __restrict__ ws)
{
  // region A: P (4 waves x 16x136 = 8704 shorts) overlays K (8192 shorts)
  // region B: V (8192 shorts, col-swizzled)
  __shared__ __align__(16) short lds[16896];   // 33792 B
  short* lsK = lds;
  short* lsP = lds;
  short* lsV = lds + 8704;
  int bx = blockIdx.x, tid = threadIdx.x;
  int qq = bx >> 9, grp = bx & 511;
  int n = grp >> 3, h = grp & 7;
  int w = tid >> 6, l = tid & 63, q = l >> 4, c = l & 15;
  const short* qh = (const short*)(ws + Q_OFF) + (n * HH + h) * 256 * HDIM;
  const short* kh = (const short*)(ws + K_OFF) + (n * HH + h) * 256 * HDIM;
  const short* vt = (const short*)(ws + VT_OFF) + (n * HH + h) * HDIM * 256;
  const short* pbf = (const short*)(ws + PBF_OFF) + (h * 16 + qq * 4 + w) * 16 * 256;
  short* os = (short*)(ws + O_OFF);
  const float scl2 = 0.17677669529663687f * 1.44269504088896f;  // 1/sqrt(32)*log2e
  int i0 = qq * 64 + w * 16;             // this wave's 16 query rows

  // Q fragment + pb fragments: issue BEFORE staging so they drain with it
  short8 aq = *(const short8*)&qh[(i0 + c) * HDIM + q * 8];
  short4v pv[16];
#pragma unroll
  for (int jt = 0; jt < 16; jt++)
    pv[jt] = *(const short4v*)&pbf[(jt * 64 + l) * 4];

#pragma unroll
  for (int i = 0; i < 4; i++) {
    int ci = i * 256 + tid;
    ld_lds16(&kh[ci * 8], &lsK[ci * 8]);
  }
#pragma unroll
  for (int i = 0; i < 4; i++) {
    int ci = i * 256 + tid;
    int row = ci >> 5, j = ci & 31;
    int sj = j ^ (row & 7);
    ld_lds16(&vt[row * 256 + sj * 8], &lsV[ci * 8]);
  }
  WAIT_VM0();
  __syncthreads();

  // swapped QK^T: s[jt][r] = S[j = jt*16+q*4+r][i0+c] (un-scaled)
  float4v s[16];
#pragma unroll
  for (int jt = 0; jt < 16; jt++) {
    short8 kf = *(const short8*)&lsK[(jt * 16 + c) * 32 + q * 8];
    s[jt] = MFMA16(kf, aq, zero4());
  }
  // scale(+log2e) + pair bias (pre-x log2e, transposed fragments)
#pragma unroll
  for (int jt = 0; jt < 16; jt++) {
#pragma unroll
    for (int r = 0; r < 4; r++)
      s[jt][r] = __builtin_fmaf(s[jt][r], scl2, b2f(pv[jt][r]));
  }
  // scalar softmax for query i0+c: in-reg trees + 2 shfls
  float t[16];
#pragma unroll
  for (int jt = 0; jt < 16; jt++)
    t[jt] = fmaxf(fmaxf(s[jt][0], s[jt][1]), fmaxf(s[jt][2], s[jt][3]));
#pragma unroll
  for (int st = 8; st >= 1; st >>= 1)
#pragma unroll
    for (int i = 0; i < st; i++) t[i] = fmaxf(t[i], t[i + st]);
  float m = fmaxf(t[0], __shfl_xor(t[0], 16, 64));
  m = fmaxf(m, __shfl_xor(m, 32, 64));
#pragma unroll
  for (int jt = 0; jt < 16; jt++) {
#pragma unroll
    for (int r = 0; r < 4; r++) s[jt][r] = exp2f(s[jt][r] - m);
    t[jt] = (s[jt][0] + s[jt][1]) + (s[jt][2] + s[jt][3]);
  }
#pragma unroll
  for (int st = 8; st >= 1; st >>= 1)
#pragma unroll
    for (int i = 0; i < st; i++) t[i] += t[i + st];
  float rs = t[0];
  rs += __shfl_xor(rs, 16, 64);
  rs += __shfl_xor(rs, 32, 64);
  float inv = 1.f / rs;

  __syncthreads();   // all waves done reading lsK before P overlays it

  // two half-passes over j: write 16x128 P slice, consume it, overwrite.
  int pw = w * 2176 + c * 136;           // wave-private P row (query i0+c)
  float4v o0 = zero4(), o1 = zero4();
#pragma unroll
  for (int ch = 0; ch < 2; ch++) {
#pragma unroll
    for (int jt2 = 0; jt2 < 8; jt2++) {
      int jt = ch * 8 + jt2;
      uint2 u;
      u.x = pkbf(s[jt][0], s[jt][1]);
      u.y = pkbf(s[jt][2], s[jt][3]);
      *(uint2*)&lsP[pw + jt2 * 16 + q * 4] = u;
    }
#pragma unroll
    for (int kk2 = 0; kk2 < 4; kk2++) {
      int kk = ch * 4 + kk2;
      short8 pf = *(const short8*)&lsP[pw + kk2 * 32 + q * 8];
      int sl0 = ((kk * 4 + q) ^ (c & 7)) * 8;
      short8 b0 = *(const short8*)&lsV[c * 256 + sl0];
      short8 b1 = *(const short8*)&lsV[(16 + c) * 256 + sl0];
      o0 = MFMA16(b0, pf, o0);
      o1 = MFMA16(b1, pf, o1);
    }
  }
  // lane (q,c): O[i0+c][d = q*4+r] (o0) and [d = 16+q*4+r] (o1)
  short* orow = &os[(n * 256 + i0 + c) * 256 + h * 32];
  short4v t0, t1;
#pragma unroll
  for (int r = 0; r < 4; r++) {
    t0[r] = f2b(o0[r] * inv);
    t1[r] = f2b(o1[r] * inv);
  }
  *(short4v*)&orow[q * 4] = t0;
  *(short4v*)&orow[16 + q * 4] = t1;
}

// ============================================================================
// K4: out-proj + bias + residual + LayerNorm. LDS-staged, 32 rows/block:
// grid 512, 2 blocks/CU.
// ============================================================================
__global__ __launch_bounds__(256) void k4_out(
    const float* __restrict__ msa, const float* __restrict__ bo,
    const float* __restrict__ gamma, const float* __restrict__ beta,
    const char* __restrict__ ws, float* __restrict__ out)
{
  __shared__ __align__(16) short lsA[32 * 128];
  __shared__ __align__(16) short lsB[256 * 128];
  __shared__ float sred[2][32][2];       // [s1|s2][row-in-block][col-half]
  int bx = blockIdx.x, tid = threadIdx.x;
  int w = tid >> 6, l = tid & 63, q = l >> 4, c = l & 15;
  int rg = w >> 1, ch2 = w & 1;          // row-group (0/1), col-half (0/1)
  int R0 = bx * 32;                      // block's 32 rows
  int Rw = R0 + rg * 16;                 // this wave's 16 rows
  int C0 = ch2 * 128;                    // this wave's 128 cols
  const short* osrc = (const short*)(ws + O_OFF);
  const short* wto  = (const short*)(ws + WT_OFF) + 3 * 65536;

  float4v acc[8];
#pragma unroll
  for (int nt = 0; nt < 8; nt++) acc[nt] = zero4();

#pragma unroll 1
  for (int kk = 0; kk < 2; kk++) {
    if (kk) __syncthreads();
#pragma unroll
    for (int i = 0; i < 2; i++) {        // A: 32 rows x 128 k
      int ci = i * 256 + tid;
      int r = ci >> 4, pos = ci & 15;
      int kc = pos ^ (r & 7);
      ld_lds16(&osrc[(R0 + r) * 256 + kk * 128 + kc * 8], &lsA[ci * 8]);
    }
#pragma unroll
    for (int i = 0; i < 16; i++) {       // B: 256 ch x 128 k
      int ci = i * 256 + tid;
      int r = ci >> 4, pos = ci & 15;
      int kc = pos ^ (r & 7);
      ld_lds16(&wto[r * 256 + kk * 128 + kc * 8], &lsB[ci * 8]);
    }
    WAIT_VM0();
    __syncthreads();
#pragma unroll
    for (int ks = 0; ks < 4; ks++) {
      int rA = rg * 16 + c;
      int physA = (ks * 4 + q) ^ (rA & 7);
      short8 af = *(const short8*)&lsA[rA * 128 + physA * 8];
#pragma unroll
      for (int nt = 0; nt < 8; nt++) {
        int rB = C0 + nt * 16 + c;
        int phys = (ks * 4 + q) ^ (rB & 7);
        short8 bf = *(const short8*)&lsB[rB * 128 + phys * 8];
        acc[nt] = MFMA16(af, bf, acc[nt]);
      }
    }
  }

  // bias + residual + stats over this wave's 128 cols
  float s1[4] = {0, 0, 0, 0}, s2[4] = {0, 0, 0, 0};
#pragma unroll
  for (int nt = 0; nt < 8; nt++) {
    float bb = bo[C0 + nt * 16 + c];
#pragma unroll
    for (int r = 0; r < 4; r++) {
      float x = acc[nt][r] + bb + msa[(Rw + q * 4 + r) * 256 + C0 + nt * 16 + c];
      acc[nt][r] = x;
      s1[r] += x;
      s2[r] = __builtin_fmaf(x, x, s2[r]);
    }
  }
#pragma unroll
  for (int r = 0; r < 4; r++) {
    s1[r] += __shfl_xor(s1[r], 1, 64); s2[r] += __shfl_xor(s2[r], 1, 64);
    s1[r] += __shfl_xor(s1[r], 2, 64); s2[r] += __shfl_xor(s2[r], 2, 64);
    s1[r] += __shfl_xor(s1[r], 4, 64); s2[r] += __shfl_xor(s2[r], 4, 64);
    s1[r] += __shfl_xor(s1[r], 8, 64); s2[r] += __shfl_xor(s2[r], 8, 64);
  }
  if (c == 0) {
#pragma unroll
    for (int r = 0; r < 4; r++) {
      sred[0][rg * 16 + q * 4 + r][ch2] = s1[r];
      sred[1][rg * 16 + q * 4 + r][ch2] = s2[r];
    }
  }
  __syncthreads();
  float mu[4], rsd[4];
#pragma unroll
  for (int r = 0; r < 4; r++) {
    int row = rg * 16 + q * 4 + r;
    float a = sred[0][row][0] + sred[0][row][1];
    float b = sred[1][row][0] + sred[1][row][1];
    float m = a * (1.f / 256.f);
    float v = __builtin_fmaf(-m, m, b * (1.f / 256.f));
    mu[r] = m;
    rsd[r] = rsqrtf(v + 1e-5f);
  }
#pragma unroll
  for (int nt = 0; nt < 8; nt++) {
    float g = gamma[nt * 16 + c + C0], bt = beta[nt * 16 + c + C0];
#pragma unroll
    for (int r = 0; r < 4; r++)
      out[(Rw + q * 4 + r) * 256 + C0 + nt * 16 + c] =
          (acc[nt][r] - mu[r]) * rsd[r] * g + bt;
  }
}

extern "C" void kernel_launch(void* const* d_in, const int* in_sizes, int n_in,
                              void* d_out, int out_size, void* d_ws, size_t ws_size,
                              hipStream_t stream)
{
  const float* msa   = (const float*)d_in[0];
  const float* pair  = (const float*)d_in[1];
  const float* Wq    = (const float*)d_in[2];
  const float* bq    = (const float*)d_in[3];
  const float* Wk    = (const float*)d_in[4];
  const float* bk    = (const float*)d_in[5];
  const float* Wv    = (const float*)d_in[6];
  const float* bv    = (const float*)d_in[7];
  const float* Wpb   = (const float*)d_in[8];
  const float* bpb   = (const float*)d_in[9];
  const float* Wo    = (const float*)d_in[10];
  const float* bo    = (const float*)d_in[11];
  const float* gamma = (const float*)d_in[12];
  const float* beta  = (const float*)d_in[13];
  char* ws = (char*)d_ws;
  float* out = (float*)d_out;

  hipLaunchKernelGGL(k1_prep, dim3(832), dim3(256), 0, stream,
                     msa, pair, Wq, Wk, Wv, Wpb, bpb, Wo, ws);
  hipLaunchKernelGGL(k2_qkv, dim3(896), dim3(256), 0, stream,
                     bq, bk, bv, ws);
  hipLaunchKernelGGL(k3_attn, dim3(2048), dim3(256), 0, stream, ws);
  hipLaunchKernelGGL(k4_out, dim3(512), dim3(256), 0, stream,
                     msa, bo, gamma, beta, ws, out);
}